// Round 1
// baseline (775.881 us; speedup 1.0000x reference)
//
#include <hip/hip_runtime.h>

#define B_  8
#define L_  4096
#define DI  192
#define NCHUNK 16
#define CLEN 256

// ---------------------------------------------------------------- in_proj GEMM
// x (32768,96) @ W^T (384,96) -> xc (32768,192) | z (32768,192)
__global__ __launch_bounds__(256) void k_inproj(
    const float* __restrict__ x, const float* __restrict__ w,
    float* __restrict__ xc, float* __restrict__ z)
{
  __shared__ float As[64*97];
  __shared__ float Ws[64*97];
  const int t  = threadIdx.x;
  const int m0 = blockIdx.x * 64;
  const int n0 = blockIdx.y * 64;
  for (int i = t; i < 64*96; i += 256) As[(i/96)*97 + (i%96)] = x[(size_t)m0*96 + i];
  for (int i = t; i < 64*96; i += 256) Ws[(i/96)*97 + (i%96)] = w[(size_t)n0*96 + i];
  __syncthreads();
  const int tx = t & 15, ty = t >> 4;
  float acc[4][4] = {};
  for (int kk = 0; kk < 96; ++kk) {
    float a[4], b[4];
#pragma unroll
    for (int i = 0; i < 4; ++i) a[i] = As[(ty*4+i)*97 + kk];
#pragma unroll
    for (int j = 0; j < 4; ++j) b[j] = Ws[(tx*4+j)*97 + kk];
#pragma unroll
    for (int i = 0; i < 4; ++i)
#pragma unroll
      for (int j = 0; j < 4; ++j) acc[i][j] = fmaf(a[i], b[j], acc[i][j]);
  }
#pragma unroll
  for (int i = 0; i < 4; ++i) {
    const int row = m0 + ty*4 + i;
#pragma unroll
    for (int j = 0; j < 4; ++j) {
      const int col = n0 + tx*4 + j;
      if (col < DI) xc[(size_t)row*DI + col]      = acc[i][j];
      else          z [(size_t)row*DI + col - DI] = acc[i][j];
    }
  }
}

// ------------------------------------------------- depthwise 3x3 conv + SiLU
__global__ __launch_bounds__(192) void k_conv(
    const float* __restrict__ xc, const float* __restrict__ cw,
    const float* __restrict__ cb, float* __restrict__ xa)
{
  const int bi = blockIdx.x;             // b*4096 + site
  const int d  = threadIdx.x;
  const int b = bi >> 12, s = bi & 4095;
  const int h = s >> 6, w = s & 63;
  float wreg[9];
#pragma unroll
  for (int i = 0; i < 9; ++i) wreg[i] = cw[d*9 + i];
  float acc = cb[d];
#pragma unroll
  for (int ky = 0; ky < 3; ++ky) {
    const int hy = h + ky - 1;
    if (hy < 0 || hy > 63) continue;
#pragma unroll
    for (int kx = 0; kx < 3; ++kx) {
      const int wx = w + kx - 1;
      if (wx < 0 || wx > 63) continue;
      acc = fmaf(xc[(size_t)((b<<12) + (hy<<6) + wx)*DI + d], wreg[ky*3+kx], acc);
    }
  }
  const float sig = 1.f / (1.f + __expf(-acc));
  xa[(size_t)bi*DI + d] = acc * sig;
}

// ------------------------------------- x_proj: per site, 4 dirs x 38 outputs
// packed record per (b,k,l): [dt0..5 | B0..15 | C0..15 | pad2], 40 floats
__global__ __launch_bounds__(64) void k_xproj(
    const float* __restrict__ xa, const float* __restrict__ xw,
    float* __restrict__ proj)
{
  __shared__ float V[64*193];
  const int t  = threadIdx.x;
  const int s0 = blockIdx.x * 64;
  for (int i = t; i < 64*192; i += 64) V[(i/192)*193 + (i%192)] = xa[(size_t)s0*192 + i];
  __syncthreads();
  const int sg = s0 + t;
  const int b = sg >> 12, s = sg & 4095;
  const int h = s >> 6, w = s & 63;
  int lk[4];
  lk[0] = s; lk[1] = (w<<6)|h; lk[2] = 4095 - s; lk[3] = 4095 - lk[1];
  const float* vp = &V[t*193];
#pragma unroll 1
  for (int k = 0; k < 4; ++k) {
    float acc[38];
#pragma unroll
    for (int c = 0; c < 38; ++c) acc[c] = 0.f;
#pragma unroll 1
    for (int r0 = 0; r0 < 192; r0 += 32) {
      float v[32];
#pragma unroll
      for (int i = 0; i < 32; ++i) v[i] = vp[r0+i];
#pragma unroll
      for (int c = 0; c < 38; ++c) {
        const float* wp = xw + (size_t)(k*38+c)*192 + r0;
        float a = acc[c];
#pragma unroll
        for (int i = 0; i < 32; ++i) a = fmaf(v[i], wp[i], a);
        acc[c] = a;
      }
    }
    float* op = proj + ((size_t)((b<<2)+k)*L_ + lk[k]) * 40;
#pragma unroll
    for (int c = 0; c < 38; ++c) op[c] = acc[c];
  }
}

// -------------------------------------------------- scan phase 1: local scan
// block = (b,k,chunk), thread = d.  Outputs decay product P and local state Hl.
__global__ __launch_bounds__(192) void k_scan1(
    const float* __restrict__ xa, const float* __restrict__ proj,
    const float* __restrict__ alog, const float* __restrict__ dtw,
    const float* __restrict__ dtb,
    float* __restrict__ P, float* __restrict__ Hl)
{
  const int blk = blockIdx.x;            // b*64 + k*16 + c
  const int c = blk & 15, k = (blk >> 4) & 3, b = blk >> 6;
  const int d = threadIdx.x;
  const int kd = k*DI + d;
  float A[16], dw[6];
#pragma unroll
  for (int n = 0; n < 16; ++n) A[n] = -__expf(alog[kd*16 + n]);
#pragma unroll
  for (int r = 0; r < 6; ++r) dw[r] = dtw[kd*6 + r];
  const float db = dtb[kd];
  float h[16], p[16];
#pragma unroll
  for (int n = 0; n < 16; ++n) { h[n] = 0.f; p[n] = 1.f; }
  const int l0 = c * CLEN;
  const float* xab = xa + (size_t)(b << 12)*DI + d;
  const float* pb  = proj + (((size_t)((b<<2)+k)) << 12)*40;
#pragma unroll 2
  for (int t = 0; t < CLEN; ++t) {
    const int l = l0 + t;
    int s;
    if (k == 0)      s = l;
    else if (k == 1) s = ((l & 63) << 6) | (l >> 6);
    else if (k == 2) s = 4095 - l;
    else { const int l2 = 4095 - l; s = ((l2 & 63) << 6) | (l2 >> 6); }
    const float u = xab[(size_t)s*DI];
    const float* pp = pb + (size_t)l*40;
    float xdt = db;
#pragma unroll
    for (int r = 0; r < 6; ++r) xdt = fmaf(dw[r], pp[r], xdt);
    const float delta = (xdt > 20.f) ? xdt : __logf(1.f + __expf(xdt));
    const float du = delta * u;
#pragma unroll
    for (int n = 0; n < 16; ++n) {
      const float dA = __expf(delta * A[n]);
      p[n] *= dA;
      h[n] = fmaf(dA, h[n], du * pp[6+n]);
    }
  }
  const size_t base = (size_t)blk * 16 * DI + d;
#pragma unroll
  for (int n = 0; n < 16; ++n) { P[base + n*DI] = p[n]; Hl[base + n*DI] = h[n]; }
}

// --------------------------------- scan phase 2: chunk combine + zero ycomb
__global__ __launch_bounds__(256) void k_scan2(
    const float* __restrict__ P, const float* __restrict__ Hl,
    float* __restrict__ hin, float* __restrict__ ycomb)
{
  const int tid = blockIdx.x * 256 + threadIdx.x;   // < 98304
  for (size_t i = tid; i < (size_t)B_*L_*DI; i += 98304) ycomb[i] = 0.f;
  const int d  = tid % DI;
  const int n  = (tid / DI) & 15;
  const int bk = tid / (DI*16);                     // 0..31
  float h = 0.f;
  for (int cc = 0; cc < NCHUNK; ++cc) {
    const size_t idx = ((size_t)(bk*NCHUNK + cc)*16 + n)*DI + d;
    hin[idx] = h;
    h = fmaf(P[idx], h, Hl[idx]);
  }
}

// ------------------------- scan phase 3: re-scan with h_in, emit y (atomic)
__global__ __launch_bounds__(192) void k_scan3(
    const float* __restrict__ xa, const float* __restrict__ proj,
    const float* __restrict__ alog, const float* __restrict__ dtw,
    const float* __restrict__ dtb, const float* __restrict__ Dv,
    const float* __restrict__ hin, float* __restrict__ ycomb)
{
  const int blk = blockIdx.x;
  const int c = blk & 15, k = (blk >> 4) & 3, b = blk >> 6;
  const int d = threadIdx.x;
  const int kd = k*DI + d;
  float A[16], dw[6];
#pragma unroll
  for (int n = 0; n < 16; ++n) A[n] = -__expf(alog[kd*16 + n]);
#pragma unroll
  for (int r = 0; r < 6; ++r) dw[r] = dtw[kd*6 + r];
  const float db = dtb[kd];
  const float Dd = Dv[kd];
  float h[16];
  const size_t base = (size_t)blk * 16 * DI + d;
#pragma unroll
  for (int n = 0; n < 16; ++n) h[n] = hin[base + n*DI];
  const int l0 = c * CLEN;
  const float* xab = xa + (size_t)(b << 12)*DI + d;
  const float* pb  = proj + (((size_t)((b<<2)+k)) << 12)*40;
#pragma unroll 2
  for (int t = 0; t < CLEN; ++t) {
    const int l = l0 + t;
    int s;
    if (k == 0)      s = l;
    else if (k == 1) s = ((l & 63) << 6) | (l >> 6);
    else if (k == 2) s = 4095 - l;
    else { const int l2 = 4095 - l; s = ((l2 & 63) << 6) | (l2 >> 6); }
    const float u = xab[(size_t)s*DI];
    const float* pp = pb + (size_t)l*40;
    float xdt = db;
#pragma unroll
    for (int r = 0; r < 6; ++r) xdt = fmaf(dw[r], pp[r], xdt);
    const float delta = (xdt > 20.f) ? xdt : __logf(1.f + __expf(xdt));
    const float du = delta * u;
    float y = 0.f;
#pragma unroll
    for (int n = 0; n < 16; ++n) {
      const float dA = __expf(delta * A[n]);
      h[n] = fmaf(dA, h[n], du * pp[6+n]);
      y = fmaf(h[n], pp[22+n], y);
    }
    y = fmaf(u, Dd, y);
    atomicAdd(&ycomb[(size_t)((b<<12) + s)*DI + d], y);
  }
}

// ----------------------------- final: LayerNorm + silu(z) gate + out_proj
__global__ __launch_bounds__(256) void k_final(
    const float* __restrict__ ycomb, const float* __restrict__ zb,
    const float* __restrict__ lng, const float* __restrict__ lnb,
    const float* __restrict__ ow, float* __restrict__ out)
{
  __shared__ float yn[64*193];
  const int t = threadIdx.x;
  const int lane = t & 63, wv = t >> 6;
  const int g0 = blockIdx.x * 64;
  for (int si = 0; si < 16; ++si) {
    const int sl = wv*16 + si;
    const int g  = g0 + sl;
    float v[3]; float sum = 0.f, sq = 0.f;
#pragma unroll
    for (int j = 0; j < 3; ++j) {
      v[j] = ycomb[(size_t)g*DI + lane*3 + j];
      sum += v[j]; sq = fmaf(v[j], v[j], sq);
    }
#pragma unroll
    for (int o = 1; o < 64; o <<= 1) { sum += __shfl_xor(sum, o); sq += __shfl_xor(sq, o); }
    const float mu = sum * (1.f/192.f);
    const float rs = rsqrtf(sq*(1.f/192.f) - mu*mu + 1e-5f);
#pragma unroll
    for (int j = 0; j < 3; ++j) {
      const int ch = lane*3 + j;
      const float zv = zb[(size_t)g*DI + ch];
      const float sz = zv / (1.f + __expf(-zv));
      yn[sl*193 + ch] = ((v[j]-mu)*rs*lng[ch] + lnb[ch]) * sz;
    }
  }
  __syncthreads();
  for (int j2 = 0; j2 < 24; ++j2) {
    const int idx = j2*256 + t;
    const int sl  = idx & 63;
    const int c2  = __builtin_amdgcn_readfirstlane(idx >> 6);   // wave-uniform
    const float* yrow = &yn[sl*193];
    const float* wrow = ow + c2*192;
    float acc = 0.f;
#pragma unroll 8
    for (int r = 0; r < 192; ++r) acc = fmaf(yrow[r], wrow[r], acc);
    out[(size_t)(g0+sl)*96 + c2] = acc;
  }
}

extern "C" void kernel_launch(void* const* d_in, const int* in_sizes, int n_in,
                              void* d_out, int out_size, void* d_ws, size_t ws_size,
                              hipStream_t stream)
{
  (void)in_sizes; (void)n_in; (void)out_size; (void)ws_size;
  const float* x    = (const float*)d_in[0];
  const float* ipw  = (const float*)d_in[1];
  const float* cw   = (const float*)d_in[2];
  const float* cb   = (const float*)d_in[3];
  const float* xpw  = (const float*)d_in[4];
  const float* dpw  = (const float*)d_in[5];
  const float* dpb  = (const float*)d_in[6];
  const float* alog = (const float*)d_in[7];
  const float* Dv   = (const float*)d_in[8];
  const float* lng  = (const float*)d_in[9];
  const float* lnb  = (const float*)d_in[10];
  const float* opw  = (const float*)d_in[11];
  float* out = (float*)d_out;

  float* ws    = (float*)d_ws;
  float* xc    = ws;                  // 6291456 f32 (recycled as ycomb)
  float* zbuf  = ws + 6291456;        // 6291456
  float* xa    = ws + 12582912;       // 6291456
  float* proj  = ws + 18874368;       // 5242880 (B*K*L*40)
  float* Pb    = ws + 24117248;       // 1572864
  float* Hlb   = ws + 25690112;       // 1572864
  float* hinb  = ws + 27262976;       // 1572864  (total ~110 MiB)
  float* ycomb = xc;

  k_inproj<<<dim3(512, 6), 256, 0, stream>>>(x, ipw, xc, zbuf);
  k_conv  <<<32768, 192, 0, stream>>>(xc, cw, cb, xa);
  k_xproj <<<512, 64, 0, stream>>>(xa, xpw, proj);
  k_scan1 <<<512, 192, 0, stream>>>(xa, proj, alog, dpw, dpb, Pb, Hlb);
  k_scan2 <<<384, 256, 0, stream>>>(Pb, Hlb, hinb, ycomb);
  k_scan3 <<<512, 192, 0, stream>>>(xa, proj, alog, dpw, dpb, Dv, hinb, ycomb);
  k_final <<<512, 256, 0, stream>>>(ycomb, zbuf, lng, lnb, opw, out);
}

// Round 2
// 536.706 us; speedup vs baseline: 1.4456x; 1.4456x over previous
//
#include <hip/hip_runtime.h>

#define B_  8
#define L_  4096
#define DI  192

// ---------------------------------------------------------------- in_proj GEMM
// x (32768,96) @ W^T (384,96) -> xc (32768,192) | z (32768,192)
__global__ __launch_bounds__(256) void k_inproj(
    const float* __restrict__ x, const float* __restrict__ w,
    float* __restrict__ xc, float* __restrict__ z)
{
  __shared__ float As[64*97];
  __shared__ float Ws[64*97];
  const int t  = threadIdx.x;
  const int m0 = blockIdx.x * 64;
  const int n0 = blockIdx.y * 64;
  for (int i = t; i < 64*96; i += 256) As[(i/96)*97 + (i%96)] = x[(size_t)m0*96 + i];
  for (int i = t; i < 64*96; i += 256) Ws[(i/96)*97 + (i%96)] = w[(size_t)n0*96 + i];
  __syncthreads();
  const int tx = t & 15, ty = t >> 4;
  float acc[4][4] = {};
  for (int kk = 0; kk < 96; ++kk) {
    float a[4], b[4];
#pragma unroll
    for (int i = 0; i < 4; ++i) a[i] = As[(ty*4+i)*97 + kk];
#pragma unroll
    for (int j = 0; j < 4; ++j) b[j] = Ws[(tx*4+j)*97 + kk];
#pragma unroll
    for (int i = 0; i < 4; ++i)
#pragma unroll
      for (int j = 0; j < 4; ++j) acc[i][j] = fmaf(a[i], b[j], acc[i][j]);
  }
#pragma unroll
  for (int i = 0; i < 4; ++i) {
    const int row = m0 + ty*4 + i;
#pragma unroll
    for (int j = 0; j < 4; ++j) {
      const int col = n0 + tx*4 + j;
      if (col < DI) xc[(size_t)row*DI + col]      = acc[i][j];
      else          z [(size_t)row*DI + col - DI] = acc[i][j];
    }
  }
}

// ------------------------------------------------- depthwise 3x3 conv + SiLU
__global__ __launch_bounds__(192) void k_conv(
    const float* __restrict__ xc, const float* __restrict__ cw,
    const float* __restrict__ cb, float* __restrict__ xa)
{
  const int bi = blockIdx.x;             // b*4096 + site
  const int d  = threadIdx.x;
  const int b = bi >> 12, s = bi & 4095;
  const int h = s >> 6, w = s & 63;
  float wreg[9];
#pragma unroll
  for (int i = 0; i < 9; ++i) wreg[i] = cw[d*9 + i];
  float acc = cb[d];
#pragma unroll
  for (int ky = 0; ky < 3; ++ky) {
    const int hy = h + ky - 1;
    if (hy < 0 || hy > 63) continue;
#pragma unroll
    for (int kx = 0; kx < 3; ++kx) {
      const int wx = w + kx - 1;
      if (wx < 0 || wx > 63) continue;
      acc = fmaf(xc[(size_t)((b<<12) + (hy<<6) + wx)*DI + d], wreg[ky*3+kx], acc);
    }
  }
  const float sig = 1.f / (1.f + __expf(-acc));
  xa[(size_t)bi*DI + d] = acc * sig;
}

// ------------------------------------- x_proj: per (site, dir), 38 outputs
// packed record per (b,k,l): [dt0..5 | B0..15 | C0..15 | pad2], 40 floats
// 256 threads: thread = (site sl = t&63, dir k = t>>6); k is wave-uniform so
// weight loads stay scalar (s_load); 4x the wave count of the old version.
__global__ __launch_bounds__(256) void k_xproj(
    const float* __restrict__ xa, const float* __restrict__ xw,
    float* __restrict__ proj)
{
  __shared__ float V[64*193];
  const int t  = threadIdx.x;
  const int s0 = blockIdx.x * 64;
  for (int i = t; i < 64*192; i += 256) V[(i/192)*193 + (i%192)] = xa[(size_t)s0*192 + i];
  __syncthreads();
  const int sl = t & 63;
  const int k  = t >> 6;                 // wave-uniform
  const int sg = s0 + sl;
  const int b = sg >> 12, s = sg & 4095;
  const int h = s >> 6, w = s & 63;
  const int swh = (w << 6) | h;
  int lk;
  if (k == 0)      lk = s;
  else if (k == 1) lk = swh;
  else if (k == 2) lk = 4095 - s;
  else             lk = 4095 - swh;
  const float* vp = &V[sl*193];
  const float* wb = xw + (size_t)k*38*192;
  float acc[38];
#pragma unroll
  for (int c = 0; c < 38; ++c) acc[c] = 0.f;
#pragma unroll 1
  for (int r0 = 0; r0 < 192; r0 += 16) {
    float v[16];
#pragma unroll
    for (int i = 0; i < 16; ++i) v[i] = vp[r0+i];
#pragma unroll
    for (int c = 0; c < 38; ++c) {
      const float* wp = wb + c*192 + r0;
      float a = acc[c];
#pragma unroll
      for (int i = 0; i < 16; ++i) a = fmaf(v[i], wp[i], a);
      acc[c] = a;
    }
  }
  float* op = proj + ((size_t)((b<<2)+k)*L_ + lk) * 40;
#pragma unroll
  for (int c = 0; c < 38; ++c) op[c] = acc[c];
}

// -------------------------------------------------- scan phase 1: local scan
// block = (b,k,chunk), thread = d.  Outputs decay product P and local state Hl.
template<int NC>
__global__ __launch_bounds__(192) void k_scan1(
    const float* __restrict__ xa, const float* __restrict__ proj,
    const float* __restrict__ alog, const float* __restrict__ dtw,
    const float* __restrict__ dtb,
    float* __restrict__ P, float* __restrict__ Hl)
{
  constexpr int CL = L_ / NC;
  const int blk = blockIdx.x;            // b*(4*NC) + k*NC + c
  const int c = blk % NC, k = (blk / NC) & 3, b = blk / (NC*4);
  const int d = threadIdx.x;
  const int kd = k*DI + d;
  float A[16], dw[6];
#pragma unroll
  for (int n = 0; n < 16; ++n) A[n] = -__expf(alog[kd*16 + n]);
#pragma unroll
  for (int r = 0; r < 6; ++r) dw[r] = dtw[kd*6 + r];
  const float db = dtb[kd];
  float h[16], p[16];
#pragma unroll
  for (int n = 0; n < 16; ++n) { h[n] = 0.f; p[n] = 1.f; }
  const int l0 = c * CL;
  const float* xab = xa + (size_t)(b << 12)*DI + d;
  const float* pb  = proj + (((size_t)((b<<2)+k)) << 12)*40;
#pragma unroll 2
  for (int t = 0; t < CL; ++t) {
    const int l = l0 + t;
    int s;
    if (k == 0)      s = l;
    else if (k == 1) s = ((l & 63) << 6) | (l >> 6);
    else if (k == 2) s = 4095 - l;
    else { const int l2 = 4095 - l; s = ((l2 & 63) << 6) | (l2 >> 6); }
    const float u = xab[(size_t)s*DI];
    const float* pp = pb + (size_t)l*40;
    float xdt = db;
#pragma unroll
    for (int r = 0; r < 6; ++r) xdt = fmaf(dw[r], pp[r], xdt);
    const float delta = (xdt > 20.f) ? xdt : __logf(1.f + __expf(xdt));
    const float du = delta * u;
#pragma unroll
    for (int n = 0; n < 16; ++n) {
      const float dA = __expf(delta * A[n]);
      p[n] *= dA;
      h[n] = fmaf(dA, h[n], du * pp[6+n]);
    }
  }
  const size_t base = (size_t)blk * 16 * DI + d;
#pragma unroll
  for (int n = 0; n < 16; ++n) { P[base + n*DI] = p[n]; Hl[base + n*DI] = h[n]; }
}

// --------------------------------- scan phase 2: chunk combine + zero ycomb
// NOTE: hin ALIASES P (read P[idx] strictly before writing hin[idx]).
template<int NC>
__global__ __launch_bounds__(256) void k_scan2(
    float* P_hin, const float* __restrict__ Hl, float* __restrict__ ycomb)
{
  const int tid = blockIdx.x * 256 + threadIdx.x;   // < 98304
  for (size_t i = tid; i < (size_t)B_*L_*DI; i += 98304) ycomb[i] = 0.f;
  const int d  = tid % DI;
  const int n  = (tid / DI) & 15;
  const int bk = tid / (DI*16);                     // 0..31
  float h = 0.f;
  for (int cc = 0; cc < NC; ++cc) {
    const size_t idx = ((size_t)(bk*NC + cc)*16 + n)*DI + d;
    const float pv = P_hin[idx];
    const float hl = Hl[idx];
    P_hin[idx] = h;                                 // hin
    h = fmaf(pv, h, hl);
  }
}

// ------------------------- scan phase 3: re-scan with h_in, emit y (atomic)
template<int NC>
__global__ __launch_bounds__(192) void k_scan3(
    const float* __restrict__ xa, const float* __restrict__ proj,
    const float* __restrict__ alog, const float* __restrict__ dtw,
    const float* __restrict__ dtb, const float* __restrict__ Dv,
    const float* __restrict__ hin, float* __restrict__ ycomb)
{
  constexpr int CL = L_ / NC;
  const int blk = blockIdx.x;
  const int c = blk % NC, k = (blk / NC) & 3, b = blk / (NC*4);
  const int d = threadIdx.x;
  const int kd = k*DI + d;
  float A[16], dw[6];
#pragma unroll
  for (int n = 0; n < 16; ++n) A[n] = -__expf(alog[kd*16 + n]);
#pragma unroll
  for (int r = 0; r < 6; ++r) dw[r] = dtw[kd*6 + r];
  const float db = dtb[kd];
  const float Dd = Dv[kd];
  float h[16];
  const size_t base = (size_t)blk * 16 * DI + d;
#pragma unroll
  for (int n = 0; n < 16; ++n) h[n] = hin[base + n*DI];
  const int l0 = c * CL;
  const float* xab = xa + (size_t)(b << 12)*DI + d;
  const float* pb  = proj + (((size_t)((b<<2)+k)) << 12)*40;
#pragma unroll 2
  for (int t = 0; t < CL; ++t) {
    const int l = l0 + t;
    int s;
    if (k == 0)      s = l;
    else if (k == 1) s = ((l & 63) << 6) | (l >> 6);
    else if (k == 2) s = 4095 - l;
    else { const int l2 = 4095 - l; s = ((l2 & 63) << 6) | (l2 >> 6); }
    const float u = xab[(size_t)s*DI];
    const float* pp = pb + (size_t)l*40;
    float xdt = db;
#pragma unroll
    for (int r = 0; r < 6; ++r) xdt = fmaf(dw[r], pp[r], xdt);
    const float delta = (xdt > 20.f) ? xdt : __logf(1.f + __expf(xdt));
    const float du = delta * u;
    float y = 0.f;
#pragma unroll
    for (int n = 0; n < 16; ++n) {
      const float dA = __expf(delta * A[n]);
      h[n] = fmaf(dA, h[n], du * pp[6+n]);
      y = fmaf(h[n], pp[22+n], y);
    }
    y = fmaf(u, Dd, y);
    atomicAdd(&ycomb[(size_t)((b<<12) + s)*DI + d], y);
  }
}

// ----------------------------- final: LayerNorm + silu(z) gate + out_proj
// Phase 1: LN+gate, store TRANSPOSED yt[r][site] (stride 68, 16B-aligned rows).
// Phase 2: register-tiled 64x96 GEMM: a[4] = one ds_read_b128, w as float4
// global loads (73 KB, L2-resident). 24 FMAs per LDS instruction.
__global__ __launch_bounds__(256) void k_final(
    const float* __restrict__ ycomb, const float* __restrict__ zb,
    const float* __restrict__ lng, const float* __restrict__ lnb,
    const float* __restrict__ ow, float* __restrict__ out)
{
  __shared__ float yt[192*68];
  const int t = threadIdx.x;
  const int lane = t & 63, wv = t >> 6;
  const int g0 = blockIdx.x * 64;
  for (int si = 0; si < 16; ++si) {
    const int sl = wv*16 + si;
    const int g  = g0 + sl;
    float v[3]; float sum = 0.f, sq = 0.f;
#pragma unroll
    for (int j = 0; j < 3; ++j) {
      v[j] = ycomb[(size_t)g*DI + lane*3 + j];
      sum += v[j]; sq = fmaf(v[j], v[j], sq);
    }
#pragma unroll
    for (int o = 1; o < 64; o <<= 1) { sum += __shfl_xor(sum, o); sq += __shfl_xor(sq, o); }
    const float mu = sum * (1.f/192.f);
    const float rs = rsqrtf(sq*(1.f/192.f) - mu*mu + 1e-5f);
#pragma unroll
    for (int j = 0; j < 3; ++j) {
      const int ch = lane*3 + j;
      const float zv = zb[(size_t)g*DI + ch];
      const float sz = zv / (1.f + __expf(-zv));
      yt[ch*68 + sl] = ((v[j]-mu)*rs*lng[ch] + lnb[ch]) * sz;
    }
  }
  __syncthreads();
  const int tx = t & 15, ty = t >> 4;    // tx -> 6 channels, ty -> 4 sites
  const int c0 = tx*6;
  float acc[4][6] = {};
#pragma unroll 1
  for (int k4 = 0; k4 < 192; k4 += 4) {
    float4 bw[6];
#pragma unroll
    for (int j = 0; j < 6; ++j) bw[j] = *(const float4*)&ow[(c0+j)*192 + k4];
#pragma unroll
    for (int i4 = 0; i4 < 4; ++i4) {
      const float4 a4 = *(const float4*)&yt[(k4+i4)*68 + ty*4];
      const float av[4] = {a4.x, a4.y, a4.z, a4.w};
      const float bv[6] = {
        i4==0?bw[0].x:i4==1?bw[0].y:i4==2?bw[0].z:bw[0].w,
        i4==0?bw[1].x:i4==1?bw[1].y:i4==2?bw[1].z:bw[1].w,
        i4==0?bw[2].x:i4==1?bw[2].y:i4==2?bw[2].z:bw[2].w,
        i4==0?bw[3].x:i4==1?bw[3].y:i4==2?bw[3].z:bw[3].w,
        i4==0?bw[4].x:i4==1?bw[4].y:i4==2?bw[4].z:bw[4].w,
        i4==0?bw[5].x:i4==1?bw[5].y:i4==2?bw[5].z:bw[5].w };
#pragma unroll
      for (int i = 0; i < 4; ++i)
#pragma unroll
        for (int j = 0; j < 6; ++j) acc[i][j] = fmaf(av[i], bv[j], acc[i][j]);
    }
  }
#pragma unroll
  for (int i = 0; i < 4; ++i) {
    const size_t row = (size_t)(g0 + ty*4 + i)*96 + c0;
#pragma unroll
    for (int j = 0; j < 6; ++j) out[row + j] = acc[i][j];
  }
}

extern "C" void kernel_launch(void* const* d_in, const int* in_sizes, int n_in,
                              void* d_out, int out_size, void* d_ws, size_t ws_size,
                              hipStream_t stream)
{
  (void)in_sizes; (void)n_in; (void)out_size;
  const float* x    = (const float*)d_in[0];
  const float* ipw  = (const float*)d_in[1];
  const float* cw   = (const float*)d_in[2];
  const float* cb   = (const float*)d_in[3];
  const float* xpw  = (const float*)d_in[4];
  const float* dpw  = (const float*)d_in[5];
  const float* dpb  = (const float*)d_in[6];
  const float* alog = (const float*)d_in[7];
  const float* Dv   = (const float*)d_in[8];
  const float* lng  = (const float*)d_in[9];
  const float* lnb  = (const float*)d_in[10];
  const float* opw  = (const float*)d_in[11];
  float* out = (float*)d_out;

  float* ws    = (float*)d_ws;
  float* xc    = ws;                  // 6291456 f32 (recycled as ycomb)
  float* zbuf  = ws + 6291456;        // 6291456
  float* xa    = ws + 12582912;       // 6291456
  float* proj  = ws + 18874368;       // 5242880 (B*K*L*40)
  float* Pb    = ws + 24117248;       // 98304*NC (also hin, aliased)
  float* ycomb = xc;

  k_inproj<<<dim3(512, 6), 256, 0, stream>>>(x, ipw, xc, zbuf);
  k_conv  <<<32768, 192, 0, stream>>>(xc, cw, cb, xa);
  k_xproj <<<512, 256, 0, stream>>>(xa, xpw, proj);

  const size_t need32 = (size_t)(24117248u + 2u*98304u*32u) * 4u;
  if (ws_size >= need32) {
    constexpr int NC = 32;
    float* Hlb = Pb + (size_t)98304*NC;
    k_scan1<NC><<<8*4*NC, 192, 0, stream>>>(xa, proj, alog, dpw, dpb, Pb, Hlb);
    k_scan2<NC><<<384, 256, 0, stream>>>(Pb, Hlb, ycomb);
    k_scan3<NC><<<8*4*NC, 192, 0, stream>>>(xa, proj, alog, dpw, dpb, Dv, Pb, ycomb);
  } else {
    constexpr int NC = 16;
    float* Hlb = Pb + (size_t)98304*NC;
    k_scan1<NC><<<8*4*NC, 192, 0, stream>>>(xa, proj, alog, dpw, dpb, Pb, Hlb);
    k_scan2<NC><<<384, 256, 0, stream>>>(Pb, Hlb, ycomb);
    k_scan3<NC><<<8*4*NC, 192, 0, stream>>>(xa, proj, alog, dpw, dpb, Dv, Pb, ycomb);
  }
  k_final<<<512, 256, 0, stream>>>(ycomb, zbuf, lng, lnb, opw, out);
}

// Round 3
// 490.406 us; speedup vs baseline: 1.5821x; 1.0944x over previous
//
#include <hip/hip_runtime.h>

#define B_  8
#define L_  4096
#define DI  192
#define LOG2E 1.44269504f

#if __has_builtin(__builtin_amdgcn_exp2f)
#define EXP2(x) __builtin_amdgcn_exp2f(x)
#else
#define EXP2(x) __expf((x)*0.69314718f)
#endif

// ---------------------------------------------------------------- in_proj GEMM
__global__ __launch_bounds__(256) void k_inproj(
    const float* __restrict__ x, const float* __restrict__ w,
    float* __restrict__ xc, float* __restrict__ z)
{
  __shared__ float As[64*97];
  __shared__ float Ws[64*97];
  const int t  = threadIdx.x;
  const int m0 = blockIdx.x * 64;
  const int n0 = blockIdx.y * 64;
  for (int i = t; i < 64*96; i += 256) As[(i/96)*97 + (i%96)] = x[(size_t)m0*96 + i];
  for (int i = t; i < 64*96; i += 256) Ws[(i/96)*97 + (i%96)] = w[(size_t)n0*96 + i];
  __syncthreads();
  const int tx = t & 15, ty = t >> 4;
  float acc[4][4] = {};
  for (int kk = 0; kk < 96; ++kk) {
    float a[4], b[4];
#pragma unroll
    for (int i = 0; i < 4; ++i) a[i] = As[(ty*4+i)*97 + kk];
#pragma unroll
    for (int j = 0; j < 4; ++j) b[j] = Ws[(tx*4+j)*97 + kk];
#pragma unroll
    for (int i = 0; i < 4; ++i)
#pragma unroll
      for (int j = 0; j < 4; ++j) acc[i][j] = fmaf(a[i], b[j], acc[i][j]);
  }
#pragma unroll
  for (int i = 0; i < 4; ++i) {
    const int row = m0 + ty*4 + i;
#pragma unroll
    for (int j = 0; j < 4; ++j) {
      const int col = n0 + tx*4 + j;
      if (col < DI) xc[(size_t)row*DI + col]      = acc[i][j];
      else          z [(size_t)row*DI + col - DI] = acc[i][j];
    }
  }
}

// ------------------------------------------------- depthwise 3x3 conv + SiLU
__global__ __launch_bounds__(192) void k_conv(
    const float* __restrict__ xc, const float* __restrict__ cw,
    const float* __restrict__ cb, float* __restrict__ xa)
{
  const int bi = blockIdx.x;
  const int d  = threadIdx.x;
  const int b = bi >> 12, s = bi & 4095;
  const int h = s >> 6, w = s & 63;
  float wreg[9];
#pragma unroll
  for (int i = 0; i < 9; ++i) wreg[i] = cw[d*9 + i];
  float acc = cb[d];
#pragma unroll
  for (int ky = 0; ky < 3; ++ky) {
    const int hy = h + ky - 1;
    if (hy < 0 || hy > 63) continue;
#pragma unroll
    for (int kx = 0; kx < 3; ++kx) {
      const int wx = w + kx - 1;
      if (wx < 0 || wx > 63) continue;
      acc = fmaf(xc[(size_t)((b<<12) + (hy<<6) + wx)*DI + d], wreg[ky*3+kx], acc);
    }
  }
  const float sig = 1.f / (1.f + __expf(-acc));
  xa[(size_t)bi*DI + d] = acc * sig;
}

// ------------------------------------- x_proj: per (site, dir), 38 outputs
__global__ __launch_bounds__(256) void k_xproj(
    const float* __restrict__ xa, const float* __restrict__ xw,
    float* __restrict__ proj)
{
  __shared__ float V[64*193];
  const int t  = threadIdx.x;
  const int s0 = blockIdx.x * 64;
  for (int i = t; i < 64*192; i += 256) V[(i/192)*193 + (i%192)] = xa[(size_t)s0*192 + i];
  __syncthreads();
  const int sl = t & 63;
  const int k  = t >> 6;                 // wave-uniform
  const int sg = s0 + sl;
  const int b = sg >> 12, s = sg & 4095;
  const int h = s >> 6, w = s & 63;
  const int swh = (w << 6) | h;
  int lk;
  if (k == 0)      lk = s;
  else if (k == 1) lk = swh;
  else if (k == 2) lk = 4095 - s;
  else             lk = 4095 - swh;
  const float* vp = &V[sl*193];
  const float* wb = xw + (size_t)k*38*192;
  float acc[38];
#pragma unroll
  for (int c = 0; c < 38; ++c) acc[c] = 0.f;
#pragma unroll 1
  for (int r0 = 0; r0 < 192; r0 += 16) {
    float v[16];
#pragma unroll
    for (int i = 0; i < 16; ++i) v[i] = vp[r0+i];
#pragma unroll
    for (int c = 0; c < 38; ++c) {
      const float* wp = wb + c*192 + r0;
      float a = acc[c];
#pragma unroll
      for (int i = 0; i < 16; ++i) a = fmaf(v[i], wp[i], a);
      acc[c] = a;
    }
  }
  float* op = proj + ((size_t)((b<<2)+k)*L_ + lk) * 40;
#pragma unroll
  for (int c = 0; c < 38; ++c) op[c] = acc[c];
}

// -------------------------------------------------- scan phase 1: local scan
template<int NC>
__global__ __launch_bounds__(192) void k_scan1(
    const float* __restrict__ xa, const float* __restrict__ proj,
    const float* __restrict__ alog, const float* __restrict__ dtw,
    const float* __restrict__ dtb,
    float* __restrict__ P, float* __restrict__ Hl)
{
  constexpr int CL = L_ / NC;
  const int blk = blockIdx.x;            // b*(4*NC) + k*NC + c
  const int c = blk % NC, k = (blk / NC) & 3, b = blk / (NC*4);
  const int d = threadIdx.x;
  const int kd = k*DI + d;
  const int rev = (k >> 1) & 1, sw = k & 1;
  float A2[16], dw[6];
#pragma unroll
  for (int n = 0; n < 16; ++n) A2[n] = -__expf(alog[kd*16 + n]) * LOG2E;
#pragma unroll
  for (int r = 0; r < 6; ++r) dw[r] = dtw[kd*6 + r];
  const float db = dtb[kd];
  float h[16], p[16];
#pragma unroll
  for (int n = 0; n < 16; ++n) { h[n] = 0.f; p[n] = 1.f; }
  const int l0 = c * CL;
  const float* xab = xa + (size_t)(b << 12)*DI + d;
  const float* pb  = proj + (((size_t)((b<<2)+k)) << 12)*40;
#pragma unroll 2
  for (int t = 0; t < CL; ++t) {
    const int l = l0 + t;
    const int l2 = rev ? 4095 - l : l;
    const int s  = sw ? (((l2 & 63) << 6) | (l2 >> 6)) : l2;
    const float u = xab[(size_t)s*DI];
    const float* pp = pb + (size_t)l*40;
    float xdt = db;
#pragma unroll
    for (int r = 0; r < 6; ++r) xdt = fmaf(dw[r], pp[r], xdt);
    const float delta = (xdt > 20.f) ? xdt : __logf(1.f + __expf(xdt));
    const float du = delta * u;
#pragma unroll
    for (int n = 0; n < 16; ++n) {
      const float dA = EXP2(delta * A2[n]);
      p[n] *= dA;
      h[n] = fmaf(dA, h[n], du * pp[6+n]);
    }
  }
  const size_t base = (size_t)blk * 16 * DI + d;
#pragma unroll
  for (int n = 0; n < 16; ++n) { P[base + n*DI] = p[n]; Hl[base + n*DI] = h[n]; }
}

// --------------------------------- scan phase 2: chunk combine (+opt zero)
// hin MAY alias P (reads P[idx]/Hl[idx] strictly before writing hin[idx]).
template<int NC, bool ZERO>
__global__ __launch_bounds__(256) void k_scan2(
    const float* P, const float* __restrict__ Hl, float* hin,
    float* __restrict__ ycomb)
{
  const int tid = blockIdx.x * 256 + threadIdx.x;   // < 98304
  if (ZERO)
    for (size_t i = tid; i < (size_t)B_*L_*DI; i += 98304) ycomb[i] = 0.f;
  const int d  = tid % DI;
  const int n  = (tid / DI) & 15;
  const int bk = tid / (DI*16);                     // 0..31
  float h = 0.f;
  for (int cc = 0; cc < NC; ++cc) {
    const size_t idx = ((size_t)(bk*NC + cc)*16 + n)*DI + d;
    const float pv = P[idx];
    const float hl = Hl[idx];
    hin[idx] = h;
    h = fmaf(pv, h, hl);
  }
}

// ---------------- scan phase 3 (paired): k in {pr, pr+2}, no atomics.
// Sub-scan A (k=pr) plain-stores y rows; sub-scan B (k=pr+2) visits the same
// rows (same thread!) in reverse and does load-add-store. pr=0 -> y02 indexed
// by site; pr=1 -> y13 indexed by k=1 scan order (column-major sites).
template<int NC, int HALF>
__device__ __forceinline__ void subscan3(
    int b, int pr, int c, int d,
    const float* __restrict__ xab, const float* __restrict__ proj,
    const float* __restrict__ alog, const float* __restrict__ dtw,
    const float* __restrict__ dtb, const float* __restrict__ Dv,
    const float* __restrict__ hin, float* __restrict__ yb)
{
  constexpr int CL = L_ / NC;
  const int k  = pr + 2*HALF;
  const int cc = HALF ? (NC-1-c) : c;
  const int kd = k*DI + d;
  float A2[16], dw[6];
#pragma unroll
  for (int n = 0; n < 16; ++n) A2[n] = -__expf(alog[kd*16 + n]) * LOG2E;
#pragma unroll
  for (int r = 0; r < 6; ++r) dw[r] = dtw[kd*6 + r];
  const float db = dtb[kd];
  const float Dd = Dv[kd];
  const int blkh = ((b*4 + k)*NC + cc);
  const size_t base = (size_t)blkh * 16 * DI + d;
  float h[16];
#pragma unroll
  for (int n = 0; n < 16; ++n) h[n] = hin[base + n*DI];
  const float* pb = proj + (((size_t)((b<<2)+k)) << 12)*40;
  const int l0 = cc * CL;
#pragma unroll 2
  for (int t = 0; t < CL; ++t) {
    const int l  = l0 + t;
    const int l2 = HALF ? 4095 - l : l;                       // output row
    const int s  = pr ? (((l2 & 63) << 6) | (l2 >> 6)) : l2;  // u site
    const float u = xab[(size_t)s*DI];
    const float* pp = pb + (size_t)l*40;
    float xdt = db;
#pragma unroll
    for (int r = 0; r < 6; ++r) xdt = fmaf(dw[r], pp[r], xdt);
    const float delta = (xdt > 20.f) ? xdt : __logf(1.f + __expf(xdt));
    const float du = delta * u;
    float y = 0.f;
#pragma unroll
    for (int n = 0; n < 16; ++n) {
      const float dA = EXP2(delta * A2[n]);
      h[n] = fmaf(dA, h[n], du * pp[6+n]);
      y = fmaf(h[n], pp[22+n], y);
    }
    y = fmaf(u, Dd, y);
    float* yp = yb + ((size_t)(b<<12) + l2)*DI + d;
    if (HALF == 0) *yp = y;
    else           *yp += y;      // same thread wrote this row in HALF==0
  }
}

template<int NC>
__global__ __launch_bounds__(192) void k_scan3p(
    const float* __restrict__ xa, const float* __restrict__ proj,
    const float* __restrict__ alog, const float* __restrict__ dtw,
    const float* __restrict__ dtb, const float* __restrict__ Dv,
    const float* __restrict__ hin, float* __restrict__ y02,
    float* __restrict__ y13)
{
  const int blk = blockIdx.x;            // (b*2 + pr)*NC + c
  const int c  = blk % NC;
  const int pr = (blk / NC) & 1;
  const int b  = blk / (2*NC);
  const int d  = threadIdx.x;
  const float* xab = xa + (size_t)(b << 12)*DI + d;
  float* yb = pr ? y13 : y02;
  subscan3<NC,0>(b, pr, c, d, xab, proj, alog, dtw, dtb, Dv, hin, yb);
  subscan3<NC,1>(b, pr, c, d, xab, proj, alog, dtw, dtb, Dv, hin, yb);
}

// ------------------------- scan phase 3 (atomic fallback, round-2 scheme)
template<int NC>
__global__ __launch_bounds__(192) void k_scan3a(
    const float* __restrict__ xa, const float* __restrict__ proj,
    const float* __restrict__ alog, const float* __restrict__ dtw,
    const float* __restrict__ dtb, const float* __restrict__ Dv,
    const float* __restrict__ hin, float* __restrict__ ycomb)
{
  constexpr int CL = L_ / NC;
  const int blk = blockIdx.x;
  const int c = blk % NC, k = (blk / NC) & 3, b = blk / (NC*4);
  const int d = threadIdx.x;
  const int kd = k*DI + d;
  const int rev = (k >> 1) & 1, sw = k & 1;
  float A2[16], dw[6];
#pragma unroll
  for (int n = 0; n < 16; ++n) A2[n] = -__expf(alog[kd*16 + n]) * LOG2E;
#pragma unroll
  for (int r = 0; r < 6; ++r) dw[r] = dtw[kd*6 + r];
  const float db = dtb[kd];
  const float Dd = Dv[kd];
  float h[16];
  const size_t base = (size_t)blk * 16 * DI + d;
#pragma unroll
  for (int n = 0; n < 16; ++n) h[n] = hin[base + n*DI];
  const int l0 = c * CL;
  const float* xab = xa + (size_t)(b << 12)*DI + d;
  const float* pb  = proj + (((size_t)((b<<2)+k)) << 12)*40;
#pragma unroll 2
  for (int t = 0; t < CL; ++t) {
    const int l = l0 + t;
    const int l2 = rev ? 4095 - l : l;
    const int s  = sw ? (((l2 & 63) << 6) | (l2 >> 6)) : l2;
    const float u = xab[(size_t)s*DI];
    const float* pp = pb + (size_t)l*40;
    float xdt = db;
#pragma unroll
    for (int r = 0; r < 6; ++r) xdt = fmaf(dw[r], pp[r], xdt);
    const float delta = (xdt > 20.f) ? xdt : __logf(1.f + __expf(xdt));
    const float du = delta * u;
    float y = 0.f;
#pragma unroll
    for (int n = 0; n < 16; ++n) {
      const float dA = EXP2(delta * A2[n]);
      h[n] = fmaf(dA, h[n], du * pp[6+n]);
      y = fmaf(h[n], pp[22+n], y);
    }
    y = fmaf(u, Dd, y);
    atomicAdd(&ycomb[(size_t)((b<<12) + s)*DI + d], y);
  }
}

// ----------------------------- final: LayerNorm + silu(z) gate + out_proj
// MODE 0: y = y02[site] + y13[swh(site)].  MODE 1: y = ycomb[site].
template<int MODE>
__global__ __launch_bounds__(256) void k_final(
    const float* __restrict__ y02, const float* __restrict__ y13,
    const float* __restrict__ zb,
    const float* __restrict__ lng, const float* __restrict__ lnb,
    const float* __restrict__ ow, float* __restrict__ out)
{
  __shared__ float yt[192*68];
  const int t = threadIdx.x;
  const int lane = t & 63, wv = t >> 6;
  const int g0 = blockIdx.x * 64;
  for (int si = 0; si < 16; ++si) {
    const int sl = wv*16 + si;
    const int g  = g0 + sl;
    const int s  = g & 4095;
    const size_t r13 = (size_t)(g & ~4095) | (((s & 63) << 6) | (s >> 6));
    float v[3]; float sum = 0.f, sq = 0.f;
#pragma unroll
    for (int j = 0; j < 3; ++j) {
      const int ch = lane*3 + j;
      float vv = y02[(size_t)g*DI + ch];
      if (MODE == 0) vv += y13[r13*DI + ch];
      v[j] = vv;
      sum += vv; sq = fmaf(vv, vv, sq);
    }
#pragma unroll
    for (int o = 1; o < 64; o <<= 1) { sum += __shfl_xor(sum, o); sq += __shfl_xor(sq, o); }
    const float mu = sum * (1.f/192.f);
    const float rs = rsqrtf(sq*(1.f/192.f) - mu*mu + 1e-5f);
#pragma unroll
    for (int j = 0; j < 3; ++j) {
      const int ch = lane*3 + j;
      const float zv = zb[(size_t)g*DI + ch];
      const float sz = zv / (1.f + __expf(-zv));
      yt[ch*68 + sl] = ((v[j]-mu)*rs*lng[ch] + lnb[ch]) * sz;
    }
  }
  __syncthreads();
  const int tx = t & 15, ty = t >> 4;
  const int c0 = tx*6;
  float acc[4][6] = {};
#pragma unroll 1
  for (int k4 = 0; k4 < 192; k4 += 4) {
    float4 bw[6];
#pragma unroll
    for (int j = 0; j < 6; ++j) bw[j] = *(const float4*)&ow[(c0+j)*192 + k4];
#pragma unroll
    for (int i4 = 0; i4 < 4; ++i4) {
      const float4 a4 = *(const float4*)&yt[(k4+i4)*68 + ty*4];
      const float av[4] = {a4.x, a4.y, a4.z, a4.w};
      const float bv[6] = {
        i4==0?bw[0].x:i4==1?bw[0].y:i4==2?bw[0].z:bw[0].w,
        i4==0?bw[1].x:i4==1?bw[1].y:i4==2?bw[1].z:bw[1].w,
        i4==0?bw[2].x:i4==1?bw[2].y:i4==2?bw[2].z:bw[2].w,
        i4==0?bw[3].x:i4==1?bw[3].y:i4==2?bw[3].z:bw[3].w,
        i4==0?bw[4].x:i4==1?bw[4].y:i4==2?bw[4].z:bw[4].w,
        i4==0?bw[5].x:i4==1?bw[5].y:i4==2?bw[5].z:bw[5].w };
#pragma unroll
      for (int i = 0; i < 4; ++i)
#pragma unroll
        for (int j = 0; j < 6; ++j) acc[i][j] = fmaf(av[i], bv[j], acc[i][j]);
    }
  }
#pragma unroll
  for (int i = 0; i < 4; ++i) {
    const size_t row = (size_t)(g0 + ty*4 + i)*96 + c0;
#pragma unroll
    for (int j = 0; j < 6; ++j) out[row + j] = acc[i][j];
  }
}

extern "C" void kernel_launch(void* const* d_in, const int* in_sizes, int n_in,
                              void* d_out, int out_size, void* d_ws, size_t ws_size,
                              hipStream_t stream)
{
  (void)in_sizes; (void)n_in; (void)out_size;
  const float* x    = (const float*)d_in[0];
  const float* ipw  = (const float*)d_in[1];
  const float* cw   = (const float*)d_in[2];
  const float* cb   = (const float*)d_in[3];
  const float* xpw  = (const float*)d_in[4];
  const float* dpw  = (const float*)d_in[5];
  const float* dpb  = (const float*)d_in[6];
  const float* alog = (const float*)d_in[7];
  const float* Dv   = (const float*)d_in[8];
  const float* lng  = (const float*)d_in[9];
  const float* lnb  = (const float*)d_in[10];
  const float* opw  = (const float*)d_in[11];
  float* out = (float*)d_out;

  float* ws    = (float*)d_ws;
  float* xc    = ws;                  // 6291456 (recycled: y02 / ycomb)
  float* zbuf  = ws + 6291456;        // 6291456
  float* xa    = ws + 12582912;       // 6291456
  float* proj  = ws + 18874368;       // 5242880
  float* after = ws + 24117248;       // scan scratch region

  k_inproj<<<dim3(512, 6), 256, 0, stream>>>(x, ipw, xc, zbuf);
  k_conv  <<<32768, 192, 0, stream>>>(xc, cw, cb, xa);
  k_xproj <<<512, 256, 0, stream>>>(xa, xpw, proj);

  const size_t needA  = 36700160ull * 4;  // NC64 paired (P,Hl; y13 aliases Hl)
  const size_t needA2 = 33554432ull * 4;  // NC32 paired (hin,P,Hl; y13 = P..Hl)
  const size_t needB  = 30408704ull * 4;  // NC32 atomic

  if (ws_size >= needA) {
    constexpr int NC = 64;
    float* Pb  = after;                       // 6291456 (also hin)
    float* Hlb = after + (size_t)98304*NC;    // 6291456 (recycled: y13)
    k_scan1<NC><<<8*4*NC, 192, 0, stream>>>(xa, proj, alog, dpw, dpb, Pb, Hlb);
    k_scan2<NC,false><<<384, 256, 0, stream>>>(Pb, Hlb, Pb, nullptr);
    k_scan3p<NC><<<8*2*NC, 192, 0, stream>>>(xa, proj, alog, dpw, dpb, Dv, Pb, xc, Hlb);
    k_final<0><<<512, 256, 0, stream>>>(xc, Hlb, zbuf, lng, lnb, opw, out);
  } else if (ws_size >= needA2) {
    constexpr int NC = 32;
    float* hinb = after;                      // 3145728
    float* Pb   = after + (size_t)98304*NC;   // 3145728
    float* Hlb  = Pb    + (size_t)98304*NC;   // 3145728
    float* y13  = Pb;                         // P..Hl = 6291456 after scan2
    k_scan1<NC><<<8*4*NC, 192, 0, stream>>>(xa, proj, alog, dpw, dpb, Pb, Hlb);
    k_scan2<NC,false><<<384, 256, 0, stream>>>(Pb, Hlb, hinb, nullptr);
    k_scan3p<NC><<<8*2*NC, 192, 0, stream>>>(xa, proj, alog, dpw, dpb, Dv, hinb, xc, y13);
    k_final<0><<<512, 256, 0, stream>>>(xc, y13, zbuf, lng, lnb, opw, out);
  } else if (ws_size >= needB) {
    constexpr int NC = 32;
    float* Pb  = after;
    float* Hlb = after + (size_t)98304*NC;
    k_scan1<NC><<<8*4*NC, 192, 0, stream>>>(xa, proj, alog, dpw, dpb, Pb, Hlb);
    k_scan2<NC,true><<<384, 256, 0, stream>>>(Pb, Hlb, Pb, xc);
    k_scan3a<NC><<<8*4*NC, 192, 0, stream>>>(xa, proj, alog, dpw, dpb, Dv, Pb, xc);
    k_final<1><<<512, 256, 0, stream>>>(xc, nullptr, zbuf, lng, lnb, opw, out);
  } else {
    constexpr int NC = 16;
    float* Pb  = after;
    float* Hlb = after + (size_t)98304*NC;
    k_scan1<NC><<<8*4*NC, 192, 0, stream>>>(xa, proj, alog, dpw, dpb, Pb, Hlb);
    k_scan2<NC,true><<<384, 256, 0, stream>>>(Pb, Hlb, Pb, xc);
    k_scan3a<NC><<<8*4*NC, 192, 0, stream>>>(xa, proj, alog, dpw, dpb, Dv, Pb, xc);
    k_final<1><<<512, 256, 0, stream>>>(xc, nullptr, zbuf, lng, lnb, opw, out);
  }
}

// Round 4
// 489.417 us; speedup vs baseline: 1.5853x; 1.0020x over previous
//
#include <hip/hip_runtime.h>

#define B_  8
#define L_  4096
#define DI  192
#define LOG2E 1.44269504f

#if __has_builtin(__builtin_amdgcn_exp2f)
#define EXP2(x) __builtin_amdgcn_exp2f(x)
#else
#define EXP2(x) __expf((x)*0.69314718f)
#endif

// ---------------------------------------------------------------- in_proj GEMM
__global__ __launch_bounds__(256) void k_inproj(
    const float* __restrict__ x, const float* __restrict__ w,
    float* __restrict__ xc, float* __restrict__ z)
{
  __shared__ float As[64*97];
  __shared__ float Ws[64*97];
  const int t  = threadIdx.x;
  const int m0 = blockIdx.x * 64;
  const int n0 = blockIdx.y * 64;
  for (int i = t; i < 64*96; i += 256) As[(i/96)*97 + (i%96)] = x[(size_t)m0*96 + i];
  for (int i = t; i < 64*96; i += 256) Ws[(i/96)*97 + (i%96)] = w[(size_t)n0*96 + i];
  __syncthreads();
  const int tx = t & 15, ty = t >> 4;
  float acc[4][4] = {};
  for (int kk = 0; kk < 96; ++kk) {
    float a[4], b[4];
#pragma unroll
    for (int i = 0; i < 4; ++i) a[i] = As[(ty*4+i)*97 + kk];
#pragma unroll
    for (int j = 0; j < 4; ++j) b[j] = Ws[(tx*4+j)*97 + kk];
#pragma unroll
    for (int i = 0; i < 4; ++i)
#pragma unroll
      for (int j = 0; j < 4; ++j) acc[i][j] = fmaf(a[i], b[j], acc[i][j]);
  }
#pragma unroll
  for (int i = 0; i < 4; ++i) {
    const int row = m0 + ty*4 + i;
#pragma unroll
    for (int j = 0; j < 4; ++j) {
      const int col = n0 + tx*4 + j;
      if (col < DI) xc[(size_t)row*DI + col]      = acc[i][j];
      else          z [(size_t)row*DI + col - DI] = acc[i][j];
    }
  }
}

// ------------------------------------------------- depthwise 3x3 conv + SiLU
__global__ __launch_bounds__(192) void k_conv(
    const float* __restrict__ xc, const float* __restrict__ cw,
    const float* __restrict__ cb, float* __restrict__ xa)
{
  const int bi = blockIdx.x;
  const int d  = threadIdx.x;
  const int b = bi >> 12, s = bi & 4095;
  const int h = s >> 6, w = s & 63;
  float wreg[9];
#pragma unroll
  for (int i = 0; i < 9; ++i) wreg[i] = cw[d*9 + i];
  float acc = cb[d];
#pragma unroll
  for (int ky = 0; ky < 3; ++ky) {
    const int hy = h + ky - 1;
    if (hy < 0 || hy > 63) continue;
#pragma unroll
    for (int kx = 0; kx < 3; ++kx) {
      const int wx = w + kx - 1;
      if (wx < 0 || wx > 63) continue;
      acc = fmaf(xc[(size_t)((b<<12) + (hy<<6) + wx)*DI + d], wreg[ky*3+kx], acc);
    }
  }
  const float sig = 1.f / (1.f + __expf(-acc));
  xa[(size_t)bi*DI + d] = acc * sig;
}

// ------------------------------------- x_proj: per (site, dir, r-half)
// 512 threads = 64 sites x 4 dirs x 2 halves; k,half wave-uniform -> weight
// loads stay scalar. Halves reduced through LDS (stride-39, conflict-free),
// reusing the V staging buffer after a sync.
__global__ __launch_bounds__(512) void k_xproj(
    const float* __restrict__ xa, const float* __restrict__ xw,
    float* __restrict__ proj)
{
  __shared__ float SM[64*193];           // phase 1: V[site][192] (stride 193)
  const int t  = threadIdx.x;
  const int s0 = blockIdx.x * 64;
  for (int i4 = t; i4 < 64*48; i4 += 512) {
    const int row = i4 / 48, q = (i4 % 48) * 4;
    const float4 v = *(const float4*)&xa[(size_t)(s0+row)*192 + q];
    float* dst = &SM[row*193 + q];
    dst[0] = v.x; dst[1] = v.y; dst[2] = v.z; dst[3] = v.w;
  }
  __syncthreads();
  const int sl   = t & 63;
  const int k    = (t >> 6) & 3;         // wave-uniform
  const int half = t >> 8;               // wave-uniform
  const float* vp = &SM[sl*193 + half*96];
  const float* wb = xw + (size_t)k*38*192 + half*96;
  float acc[38];
#pragma unroll
  for (int c = 0; c < 38; ++c) acc[c] = 0.f;
#pragma unroll 1
  for (int r0 = 0; r0 < 96; r0 += 16) {
    float v[16];
#pragma unroll
    for (int i = 0; i < 16; ++i) v[i] = vp[r0+i];
#pragma unroll
    for (int c = 0; c < 38; ++c) {
      const float* wp = wb + c*192 + r0;
      float a = acc[c];
#pragma unroll
      for (int i = 0; i < 16; ++i) a = fmaf(v[i], wp[i], a);
      acc[c] = a;
    }
  }
  __syncthreads();                       // all V reads done; reuse SM
  float* red = SM;                       // 256*39 = 9984 floats < 64*193
  if (half) {
#pragma unroll
    for (int c = 0; c < 38; ++c) red[(k*64+sl)*39 + c] = acc[c];
  }
  __syncthreads();
  if (!half) {
#pragma unroll
    for (int c = 0; c < 38; ++c) acc[c] += red[(k*64+sl)*39 + c];
    const int sg = s0 + sl;
    const int b = sg >> 12, s = sg & 4095;
    const int h = s >> 6, w = s & 63;
    const int swh = (w << 6) | h;
    int lk;
    if (k == 0)      lk = s;
    else if (k == 1) lk = swh;
    else if (k == 2) lk = 4095 - s;
    else             lk = 4095 - swh;
    float* op = proj + ((size_t)((b<<2)+k)*L_ + lk) * 40;
#pragma unroll
    for (int c = 0; c < 38; ++c) op[c] = acc[c];
  }
}

// -------------------------------------------------- scan phase 1: local scan
template<int NC>
__global__ __launch_bounds__(192) void k_scan1(
    const float* __restrict__ xa, const float* __restrict__ proj,
    const float* __restrict__ alog, const float* __restrict__ dtw,
    const float* __restrict__ dtb,
    float* __restrict__ P, float* __restrict__ Hl)
{
  constexpr int CL = L_ / NC;
  const int blk = blockIdx.x;            // b*(4*NC) + k*NC + c
  const int c = blk % NC, k = (blk / NC) & 3, b = blk / (NC*4);
  const int d = threadIdx.x;
  const int kd = k*DI + d;
  const int rev = (k >> 1) & 1, sw = k & 1;
  float A2[16], dw[6];
#pragma unroll
  for (int n = 0; n < 16; ++n) A2[n] = -__expf(alog[kd*16 + n]) * LOG2E;
#pragma unroll
  for (int r = 0; r < 6; ++r) dw[r] = dtw[kd*6 + r];
  const float db = dtb[kd];
  float h[16], p[16];
#pragma unroll
  for (int n = 0; n < 16; ++n) { h[n] = 0.f; p[n] = 1.f; }
  const int l0 = c * CL;
  const float* xab = xa + (size_t)(b << 12)*DI + d;
  const float* pb  = proj + (((size_t)((b<<2)+k)) << 12)*40;
#pragma unroll 2
  for (int t = 0; t < CL; ++t) {
    const int l = l0 + t;
    const int l2 = rev ? 4095 - l : l;
    const int s  = sw ? (((l2 & 63) << 6) | (l2 >> 6)) : l2;
    const float u = xab[(size_t)s*DI];
    const float* pp = pb + (size_t)l*40;
    float xdt = db;
#pragma unroll
    for (int r = 0; r < 6; ++r) xdt = fmaf(dw[r], pp[r], xdt);
    const float delta = (xdt > 20.f) ? xdt : __logf(1.f + __expf(xdt));
    const float du = delta * u;
#pragma unroll
    for (int n = 0; n < 16; ++n) {
      const float dA = EXP2(delta * A2[n]);
      p[n] *= dA;
      h[n] = fmaf(dA, h[n], du * pp[6+n]);
    }
  }
  const size_t base = (size_t)blk * 16 * DI + d;
#pragma unroll
  for (int n = 0; n < 16; ++n) { P[base + n*DI] = p[n]; Hl[base + n*DI] = h[n]; }
}

// --------------------------------- scan phase 2: chunk combine (+opt zero)
// hin MAY alias P (reads P[idx]/Hl[idx] strictly before writing hin[idx]).
template<int NC, bool ZERO>
__global__ __launch_bounds__(256) void k_scan2(
    const float* P, const float* __restrict__ Hl, float* hin,
    float* __restrict__ ycomb)
{
  const int tid = blockIdx.x * 256 + threadIdx.x;   // < 98304
  if (ZERO)
    for (size_t i = tid; i < (size_t)B_*L_*DI; i += 98304) ycomb[i] = 0.f;
  const int d  = tid % DI;
  const int n  = (tid / DI) & 15;
  const int bk = tid / (DI*16);                     // 0..31
  float h = 0.f;
  for (int cc = 0; cc < NC; ++cc) {
    const size_t idx = ((size_t)(bk*NC + cc)*16 + n)*DI + d;
    const float pv = P[idx];
    const float hl = Hl[idx];
    hin[idx] = h;
    h = fmaf(pv, h, hl);
  }
}

// ---------------- scan phase 3 (paired): k in {pr, pr+2}, no atomics.
template<int NC, int HALF>
__device__ __forceinline__ void subscan3(
    int b, int pr, int c, int d,
    const float* __restrict__ xab, const float* __restrict__ proj,
    const float* __restrict__ alog, const float* __restrict__ dtw,
    const float* __restrict__ dtb, const float* __restrict__ Dv,
    const float* __restrict__ hin, float* __restrict__ yb)
{
  constexpr int CL = L_ / NC;
  const int k  = pr + 2*HALF;
  const int cc = HALF ? (NC-1-c) : c;
  const int kd = k*DI + d;
  float A2[16], dw[6];
#pragma unroll
  for (int n = 0; n < 16; ++n) A2[n] = -__expf(alog[kd*16 + n]) * LOG2E;
#pragma unroll
  for (int r = 0; r < 6; ++r) dw[r] = dtw[kd*6 + r];
  const float db = dtb[kd];
  const float Dd = Dv[kd];
  const int blkh = ((b*4 + k)*NC + cc);
  const size_t base = (size_t)blkh * 16 * DI + d;
  float h[16];
#pragma unroll
  for (int n = 0; n < 16; ++n) h[n] = hin[base + n*DI];
  const float* pb = proj + (((size_t)((b<<2)+k)) << 12)*40;
  const int l0 = cc * CL;
#pragma unroll 2
  for (int t = 0; t < CL; ++t) {
    const int l  = l0 + t;
    const int l2 = HALF ? 4095 - l : l;                       // output row
    const int s  = pr ? (((l2 & 63) << 6) | (l2 >> 6)) : l2;  // u site
    const float u = xab[(size_t)s*DI];
    const float* pp = pb + (size_t)l*40;
    float xdt = db;
#pragma unroll
    for (int r = 0; r < 6; ++r) xdt = fmaf(dw[r], pp[r], xdt);
    const float delta = (xdt > 20.f) ? xdt : __logf(1.f + __expf(xdt));
    const float du = delta * u;
    float y = 0.f;
#pragma unroll
    for (int n = 0; n < 16; ++n) {
      const float dA = EXP2(delta * A2[n]);
      h[n] = fmaf(dA, h[n], du * pp[6+n]);
      y = fmaf(h[n], pp[22+n], y);
    }
    y = fmaf(u, Dd, y);
    float* yp = yb + ((size_t)(b<<12) + l2)*DI + d;
    if (HALF == 0) *yp = y;
    else           *yp += y;      // same thread wrote this row in HALF==0
  }
}

template<int NC>
__global__ __launch_bounds__(192) void k_scan3p(
    const float* __restrict__ xa, const float* __restrict__ proj,
    const float* __restrict__ alog, const float* __restrict__ dtw,
    const float* __restrict__ dtb, const float* __restrict__ Dv,
    const float* __restrict__ hin, float* __restrict__ y02,
    float* __restrict__ y13)
{
  const int blk = blockIdx.x;            // (b*2 + pr)*NC + c
  const int c  = blk % NC;
  const int pr = (blk / NC) & 1;
  const int b  = blk / (2*NC);
  const int d  = threadIdx.x;
  const float* xab = xa + (size_t)(b << 12)*DI + d;
  float* yb = pr ? y13 : y02;
  subscan3<NC,0>(b, pr, c, d, xab, proj, alog, dtw, dtb, Dv, hin, yb);
  subscan3<NC,1>(b, pr, c, d, xab, proj, alog, dtw, dtb, Dv, hin, yb);
}

// ------------------------- scan phase 3 (atomic fallback)
template<int NC>
__global__ __launch_bounds__(192) void k_scan3a(
    const float* __restrict__ xa, const float* __restrict__ proj,
    const float* __restrict__ alog, const float* __restrict__ dtw,
    const float* __restrict__ dtb, const float* __restrict__ Dv,
    const float* __restrict__ hin, float* __restrict__ ycomb)
{
  constexpr int CL = L_ / NC;
  const int blk = blockIdx.x;
  const int c = blk % NC, k = (blk / NC) & 3, b = blk / (NC*4);
  const int d = threadIdx.x;
  const int kd = k*DI + d;
  const int rev = (k >> 1) & 1, sw = k & 1;
  float A2[16], dw[6];
#pragma unroll
  for (int n = 0; n < 16; ++n) A2[n] = -__expf(alog[kd*16 + n]) * LOG2E;
#pragma unroll
  for (int r = 0; r < 6; ++r) dw[r] = dtw[kd*6 + r];
  const float db = dtb[kd];
  const float Dd = Dv[kd];
  float h[16];
  const size_t base = (size_t)blk * 16 * DI + d;
#pragma unroll
  for (int n = 0; n < 16; ++n) h[n] = hin[base + n*DI];
  const int l0 = c * CL;
  const float* xab = xa + (size_t)(b << 12)*DI + d;
  const float* pb  = proj + (((size_t)((b<<2)+k)) << 12)*40;
#pragma unroll 2
  for (int t = 0; t < CL; ++t) {
    const int l = l0 + t;
    const int l2 = rev ? 4095 - l : l;
    const int s  = sw ? (((l2 & 63) << 6) | (l2 >> 6)) : l2;
    const float u = xab[(size_t)s*DI];
    const float* pp = pb + (size_t)l*40;
    float xdt = db;
#pragma unroll
    for (int r = 0; r < 6; ++r) xdt = fmaf(dw[r], pp[r], xdt);
    const float delta = (xdt > 20.f) ? xdt : __logf(1.f + __expf(xdt));
    const float du = delta * u;
    float y = 0.f;
#pragma unroll
    for (int n = 0; n < 16; ++n) {
      const float dA = EXP2(delta * A2[n]);
      h[n] = fmaf(dA, h[n], du * pp[6+n]);
      y = fmaf(h[n], pp[22+n], y);
    }
    y = fmaf(u, Dd, y);
    atomicAdd(&ycomb[(size_t)((b<<12) + s)*DI + d], y);
  }
}

// ----------------------------- final: LayerNorm + silu(z) gate + out_proj
template<int MODE>
__global__ __launch_bounds__(256) void k_final(
    const float* __restrict__ y02, const float* __restrict__ y13,
    const float* __restrict__ zb,
    const float* __restrict__ lng, const float* __restrict__ lnb,
    const float* __restrict__ ow, float* __restrict__ out)
{
  __shared__ float yt[192*68];
  const int t = threadIdx.x;
  const int lane = t & 63, wv = t >> 6;
  const int g0 = blockIdx.x * 64;
  for (int si = 0; si < 16; ++si) {
    const int sl = wv*16 + si;
    const int g  = g0 + sl;
    const int s  = g & 4095;
    const size_t r13 = (size_t)(g & ~4095) | (((s & 63) << 6) | (s >> 6));
    float v[3]; float sum = 0.f, sq = 0.f;
#pragma unroll
    for (int j = 0; j < 3; ++j) {
      const int ch = lane*3 + j;
      float vv = y02[(size_t)g*DI + ch];
      if (MODE == 0) vv += y13[r13*DI + ch];
      v[j] = vv;
      sum += vv; sq = fmaf(vv, vv, sq);
    }
#pragma unroll
    for (int o = 1; o < 64; o <<= 1) { sum += __shfl_xor(sum, o); sq += __shfl_xor(sq, o); }
    const float mu = sum * (1.f/192.f);
    const float rs = rsqrtf(sq*(1.f/192.f) - mu*mu + 1e-5f);
#pragma unroll
    for (int j = 0; j < 3; ++j) {
      const int ch = lane*3 + j;
      const float zv = zb[(size_t)g*DI + ch];
      const float sz = zv / (1.f + __expf(-zv));
      yt[ch*68 + sl] = ((v[j]-mu)*rs*lng[ch] + lnb[ch]) * sz;
    }
  }
  __syncthreads();
  const int tx = t & 15, ty = t >> 4;
  const int c0 = tx*6;
  float acc[4][6] = {};
#pragma unroll 1
  for (int k4 = 0; k4 < 192; k4 += 4) {
    float4 bw[6];
#pragma unroll
    for (int j = 0; j < 6; ++j) bw[j] = *(const float4*)&ow[(c0+j)*192 + k4];
#pragma unroll
    for (int i4 = 0; i4 < 4; ++i4) {
      const float4 a4 = *(const float4*)&yt[(k4+i4)*68 + ty*4];
      const float av[4] = {a4.x, a4.y, a4.z, a4.w};
      const float bv[6] = {
        i4==0?bw[0].x:i4==1?bw[0].y:i4==2?bw[0].z:bw[0].w,
        i4==0?bw[1].x:i4==1?bw[1].y:i4==2?bw[1].z:bw[1].w,
        i4==0?bw[2].x:i4==1?bw[2].y:i4==2?bw[2].z:bw[2].w,
        i4==0?bw[3].x:i4==1?bw[3].y:i4==2?bw[3].z:bw[3].w,
        i4==0?bw[4].x:i4==1?bw[4].y:i4==2?bw[4].z:bw[4].w,
        i4==0?bw[5].x:i4==1?bw[5].y:i4==2?bw[5].z:bw[5].w };
#pragma unroll
      for (int i = 0; i < 4; ++i)
#pragma unroll
        for (int j = 0; j < 6; ++j) acc[i][j] = fmaf(av[i], bv[j], acc[i][j]);
    }
  }
#pragma unroll
  for (int i = 0; i < 4; ++i) {
    const size_t row = (size_t)(g0 + ty*4 + i)*96 + c0;
#pragma unroll
    for (int j = 0; j < 6; ++j) out[row + j] = acc[i][j];
  }
}

extern "C" void kernel_launch(void* const* d_in, const int* in_sizes, int n_in,
                              void* d_out, int out_size, void* d_ws, size_t ws_size,
                              hipStream_t stream)
{
  (void)in_sizes; (void)n_in; (void)out_size;
  const float* x    = (const float*)d_in[0];
  const float* ipw  = (const float*)d_in[1];
  const float* cw   = (const float*)d_in[2];
  const float* cb   = (const float*)d_in[3];
  const float* xpw  = (const float*)d_in[4];
  const float* dpw  = (const float*)d_in[5];
  const float* dpb  = (const float*)d_in[6];
  const float* alog = (const float*)d_in[7];
  const float* Dv   = (const float*)d_in[8];
  const float* lng  = (const float*)d_in[9];
  const float* lnb  = (const float*)d_in[10];
  const float* opw  = (const float*)d_in[11];
  float* out = (float*)d_out;

  float* ws    = (float*)d_ws;
  float* xc    = ws;                  // 6291456 (recycled: y02 / ycomb)
  float* zbuf  = ws + 6291456;        // 6291456
  float* xa    = ws + 12582912;       // 6291456
  float* proj  = ws + 18874368;       // 5242880
  float* after = ws + 24117248;       // scan scratch region

  k_inproj<<<dim3(512, 6), 256, 0, stream>>>(x, ipw, xc, zbuf);
  k_conv  <<<32768, 192, 0, stream>>>(xc, cw, cb, xa);
  k_xproj <<<512, 512, 0, stream>>>(xa, xpw, proj);

  const size_t needA  = 36700160ull * 4;  // NC64 paired (P,Hl; y13 aliases Hl)
  const size_t needA2 = 33554432ull * 4;  // NC32 paired
  const size_t needB  = 30408704ull * 4;  // NC32 atomic

  if (ws_size >= needA) {
    constexpr int NC = 64;
    float* Pb  = after;                       // 6291456 (also hin)
    float* Hlb = after + (size_t)98304*NC;    // 6291456 (recycled: y13)
    k_scan1<NC><<<8*4*NC, 192, 0, stream>>>(xa, proj, alog, dpw, dpb, Pb, Hlb);
    k_scan2<NC,false><<<384, 256, 0, stream>>>(Pb, Hlb, Pb, nullptr);
    k_scan3p<NC><<<8*2*NC, 192, 0, stream>>>(xa, proj, alog, dpw, dpb, Dv, Pb, xc, Hlb);
    k_final<0><<<512, 256, 0, stream>>>(xc, Hlb, zbuf, lng, lnb, opw, out);
  } else if (ws_size >= needA2) {
    constexpr int NC = 32;
    float* hinb = after;
    float* Pb   = after + (size_t)98304*NC;
    float* Hlb  = Pb    + (size_t)98304*NC;
    float* y13  = Pb;
    k_scan1<NC><<<8*4*NC, 192, 0, stream>>>(xa, proj, alog, dpw, dpb, Pb, Hlb);
    k_scan2<NC,false><<<384, 256, 0, stream>>>(Pb, Hlb, hinb, nullptr);
    k_scan3p<NC><<<8*2*NC, 192, 0, stream>>>(xa, proj, alog, dpw, dpb, Dv, hinb, xc, y13);
    k_final<0><<<512, 256, 0, stream>>>(xc, y13, zbuf, lng, lnb, opw, out);
  } else if (ws_size >= needB) {
    constexpr int NC = 32;
    float* Pb  = after;
    float* Hlb = after + (size_t)98304*NC;
    k_scan1<NC><<<8*4*NC, 192, 0, stream>>>(xa, proj, alog, dpw, dpb, Pb, Hlb);
    k_scan2<NC,true><<<384, 256, 0, stream>>>(Pb, Hlb, Pb, xc);
    k_scan3a<NC><<<8*4*NC, 192, 0, stream>>>(xa, proj, alog, dpw, dpb, Dv, Pb, xc);
    k_final<1><<<512, 256, 0, stream>>>(xc, nullptr, zbuf, lng, lnb, opw, out);
  } else {
    constexpr int NC = 16;
    float* Pb  = after;
    float* Hlb = after + (size_t)98304*NC;
    k_scan1<NC><<<8*4*NC, 192, 0, stream>>>(xa, proj, alog, dpw, dpb, Pb, Hlb);
    k_scan2<NC,true><<<384, 256, 0, stream>>>(Pb, Hlb, Pb, xc);
    k_scan3a<NC><<<8*4*NC, 192, 0, stream>>>(xa, proj, alog, dpw, dpb, Dv, Pb, xc);
    k_final<1><<<512, 256, 0, stream>>>(xc, nullptr, zbuf, lng, lnb, opw, out);
  }
}